// Round 1
// baseline (1046.917 us; speedup 1.0000x reference)
//
#include <hip/hip_runtime.h>
#include <hip/hip_bf16.h>
#include <stdint.h>

// ============================================================================
// Attn_50233937494279: qb=q@Win^T; S=softmax(qb@c^T); ctx=S@c;
//                      out=tanh([ctx|qb]@Wout^T); returns (out[q,b,d], S[b,q,k])
//
// Precision plan: GEMM1/GEMM2 (pre-softmax) in 3-term split-bf16 (hi+lo) to
// keep logit error ~5e-4 (bf16 alone would give ~0.09 logit error -> fails
// the 2e-2 softmax threshold). GEMM4/GEMM5 (post-softmax, tanh-compressed)
// plain bf16.
//
// Workspace layout (200 MB needed), region reuse across stream-ordered phases:
//   A @ 0      (64MB): q_hi -> c_hi (after G1) -> p_bf16 (after G2)
//   B @ 64MB   (64MB): qb_hi+qb_lo -> ct (c transposed, after G2)
//   C @ 128MB  (64MB): cat = [ctx | qb] bf16
//   W @ 192MB  ( 8MB): Win_hi, Win_lo, Wout_bf16
//   d_out out-region (64MB, unused until G5): q_lo -> c_lo scratch
// ============================================================================

typedef __bf16 bf16x8 __attribute__((ext_vector_type(8)));
typedef float floatx4 __attribute__((ext_vector_type(4)));

__device__ __forceinline__ unsigned short f2bf_rne(float f) {
  unsigned int u = __float_as_uint(f);
  u += 0x7FFFu + ((u >> 16) & 1u);
  return (unsigned short)(u >> 16);
}
__device__ __forceinline__ float bf2f(unsigned short h) {
  return __uint_as_float(((unsigned int)h) << 16);
}

__device__ __forceinline__ void async_load16(const void* g, void* l) {
  __builtin_amdgcn_global_load_lds(
      (const __attribute__((address_space(1))) void*)g,
      (__attribute__((address_space(3))) void*)l,
      16, 0, 0);
}

// ----------------------------------------------------------------------------
// split fp32 -> bf16 hi/lo (lo==nullptr: plain convert). One float4 per thread.
// ----------------------------------------------------------------------------
__global__ __launch_bounds__(256) void split_kernel(
    const float* __restrict__ x, unsigned short* __restrict__ hi,
    unsigned short* __restrict__ lo, long n4)
{
  long i = (long)blockIdx.x * 256 + threadIdx.x;
  if (i >= n4) return;
  float4 v = ((const float4*)x)[i];
  ushort4 h;
  h.x = f2bf_rne(v.x); h.y = f2bf_rne(v.y);
  h.z = f2bf_rne(v.z); h.w = f2bf_rne(v.w);
  ((ushort4*)hi)[i] = h;
  if (lo) {
    ushort4 l;
    l.x = f2bf_rne(v.x - bf2f(h.x));
    l.y = f2bf_rne(v.y - bf2f(h.y));
    l.z = f2bf_rne(v.z - bf2f(h.z));
    l.w = f2bf_rne(v.w - bf2f(h.w));
    ((ushort4*)lo)[i] = l;
  }
}

// ----------------------------------------------------------------------------
// ct[b][d][k] = bf16(c[k][b][d]).  64x64 tiles via LDS.
// grid: (k_tiles=32, d_tiles=16, b=16)
// ----------------------------------------------------------------------------
__global__ __launch_bounds__(256) void transpose_kernel(
    const float* __restrict__ c, unsigned short* __restrict__ ct)
{
  __shared__ unsigned short t[64 * 68];
  int k0 = blockIdx.x * 64;
  int d0 = blockIdx.y * 64;
  int b  = blockIdx.z;
  int tid = threadIdx.x;
  #pragma unroll
  for (int p4 = 0; p4 < 4; ++p4) {
    int idx = p4 * 256 + tid;
    int kr = idx >> 4;
    int dc = (idx & 15) * 4;
    float4 v = *(const float4*)&c[(long)(k0 + kr) * 16384 + (long)b * 1024 + d0 + dc];
    ushort4 h;
    h.x = f2bf_rne(v.x); h.y = f2bf_rne(v.y);
    h.z = f2bf_rne(v.z); h.w = f2bf_rne(v.w);
    *(ushort4*)&t[kr * 68 + dc] = h;
  }
  __syncthreads();
  #pragma unroll
  for (int p4 = 0; p4 < 4; ++p4) {
    int idx = p4 * 256 + tid;
    int dr = idx >> 4;
    int kc = (idx & 15) * 4;
    ushort4 o;
    o.x = t[(kc + 0) * 68 + dr];
    o.y = t[(kc + 1) * 68 + dr];
    o.z = t[(kc + 2) * 68 + dr];
    o.w = t[(kc + 3) * 68 + dr];
    *(ushort4*)&ct[(long)b * 2097152 + (long)(d0 + dr) * 2048 + k0 + kc] = o;
  }
}

// ----------------------------------------------------------------------------
// row softmax over 2048 fp32 (in place) + bf16 copy for the ctx GEMM.
// one 256-thread block per row.
// ----------------------------------------------------------------------------
__global__ __launch_bounds__(256) void softmax_kernel(
    float* __restrict__ S, unsigned short* __restrict__ P)
{
  __shared__ float sred[8];
  long row = blockIdx.x;
  float* p = S + row * 2048;
  int tid = threadIdx.x;
  int lane = tid & 63, w = tid >> 6;
  float4 v0 = ((float4*)p)[tid];
  float4 v1 = ((float4*)p)[tid + 256];
  float m = fmaxf(fmaxf(fmaxf(v0.x, v0.y), fmaxf(v0.z, v0.w)),
                  fmaxf(fmaxf(v1.x, v1.y), fmaxf(v1.z, v1.w)));
  #pragma unroll
  for (int off = 32; off; off >>= 1) m = fmaxf(m, __shfl_xor(m, off));
  if (lane == 0) sred[w] = m;
  __syncthreads();
  m = fmaxf(fmaxf(sred[0], sred[1]), fmaxf(sred[2], sred[3]));
  v0.x = __expf(v0.x - m); v0.y = __expf(v0.y - m);
  v0.z = __expf(v0.z - m); v0.w = __expf(v0.w - m);
  v1.x = __expf(v1.x - m); v1.y = __expf(v1.y - m);
  v1.z = __expf(v1.z - m); v1.w = __expf(v1.w - m);
  float s = v0.x + v0.y + v0.z + v0.w + v1.x + v1.y + v1.z + v1.w;
  #pragma unroll
  for (int off = 32; off; off >>= 1) s += __shfl_xor(s, off);
  if (lane == 0) sred[4 + w] = s;
  __syncthreads();
  s = sred[4] + sred[5] + sred[6] + sred[7];
  float inv = 1.0f / s;
  v0.x *= inv; v0.y *= inv; v0.z *= inv; v0.w *= inv;
  v1.x *= inv; v1.y *= inv; v1.z *= inv; v1.w *= inv;
  ((float4*)p)[tid] = v0;
  ((float4*)p)[tid + 256] = v1;
  unsigned short* pp = P + row * 2048;
  ushort4 b0, b1;
  b0.x = f2bf_rne(v0.x); b0.y = f2bf_rne(v0.y);
  b0.z = f2bf_rne(v0.z); b0.w = f2bf_rne(v0.w);
  b1.x = f2bf_rne(v1.x); b1.y = f2bf_rne(v1.y);
  b1.z = f2bf_rne(v1.z); b1.w = f2bf_rne(v1.w);
  ((ushort4*)pp)[tid] = b0;
  ((ushort4*)pp)[tid + 256] = b1;
}

// ----------------------------------------------------------------------------
// Generic TN GEMM: C[bz][m][n] = sum_k A[bz][m][k] * B[bz][n][k]
// A rows: Ah + bz*sAb + m*ldA (k contiguous). B rows likewise (B^T layout).
// SPLIT=1: 3-term bf16 emulation Ah*Bh + Ah*Bl + Al*Bh (BK=32).
// SPLIT=0: plain bf16 (BK=64).
// 128x128 block tile, 256 threads (4 waves 2x2, each 64x64 via 4x4 MFMA tiles).
// Staging: global_load_lds width=16; LDS 16B-slot XOR swizzle (bank-spread on
// fragment ds_read_b128, applied on the *global source* index so the
// wave-uniform-base+lane*16 DMA constraint is respected).
// MODE 0: fp32 C            MODE 1: bf16 C
// MODE 2: fp32 tanh, row m=(b*1024+q) remapped to out[(q*16+b)*1024+n]
// MODE 3: split write: P1/P2 = hi/lo at [m*1024+n]; Cp = cat bf16 at
//         [( (m&15)*1024 + (m>>4) )*2048 + 1024 + n]   (m = q*16+b)
// ----------------------------------------------------------------------------
template<int SPLIT, int MODE>
__global__ __launch_bounds__(256, 2) void gemm_kernel(
    const unsigned short* __restrict__ Ah, const unsigned short* __restrict__ Al,
    long sAb, long ldA,
    const unsigned short* __restrict__ Bh, const unsigned short* __restrict__ Bl,
    long sBb, long ldB,
    void* __restrict__ Cp, long sCb, long ldC,
    unsigned short* __restrict__ P1, unsigned short* __restrict__ P2,
    int K)
{
  constexpr int BK  = SPLIT ? 32 : 64;
  constexpr int KB8 = BK / 8;             // 16B slots per tile row
  constexpr int ISS = (128 * KB8) / 256;  // global_load_lds issues per tile
  constexpr int NT  = SPLIT ? 4 : 2;
  __shared__ unsigned short lds[16384];   // 32 KB

  const int tid  = threadIdx.x;
  const int lane = tid & 63;
  const int w    = tid >> 6;
  const int wm   = w >> 1;
  const int wn   = w & 1;
  const int bz   = blockIdx.z;
  const long m0  = (long)blockIdx.x * 128;
  const long n0  = (long)blockIdx.y * 128;

  const unsigned short* a0 = Ah + bz * sAb + m0 * ldA;
  const unsigned short* a1 = SPLIT ? (Al + bz * sAb + m0 * ldA) : a0;
  const unsigned short* b0 = Bh + bz * sBb + n0 * ldB;
  const unsigned short* b1 = SPLIT ? (Bl + bz * sBb + n0 * ldB) : b0;

  floatx4 acc[4][4] = {};

  for (int kt = 0; kt < K; kt += BK) {
    #pragma unroll
    for (int t = 0; t < NT; ++t) {
      const unsigned short* src;
      long ld;
      int base;
      if (SPLIT) {
        src  = (t == 0) ? a0 : (t == 1) ? a1 : (t == 2) ? b0 : b1;
        ld   = (t < 2) ? ldA : ldB;
        base = t * 4096;
      } else {
        src  = (t == 0) ? a0 : b0;
        ld   = (t == 0) ? ldA : ldB;
        base = t * 8192;
      }
      #pragma unroll
      for (int it = 0; it < ISS; ++it) {
        int s   = it * 256 + tid;
        int row = s / KB8;
        int kb  = (s & (KB8 - 1)) ^ (SPLIT ? ((row >> 1) & 3) : (row & 7));
        const unsigned short* g = src + (long)row * ld + kt + kb * 8;
        async_load16(g, &lds[base + (it * 256 + w * 64) * 8]);
      }
    }
    __syncthreads();

    #pragma unroll
    for (int kk = 0; kk < BK / 32; ++kk) {
      bf16x8 fbh[4], fbl[4];
      #pragma unroll
      for (int j = 0; j < 4; ++j) {
        int r    = wn * 64 + j * 16 + (lane & 15);
        int kb   = (lane >> 4) + kk * 4;
        int slot = r * KB8 + (kb ^ (SPLIT ? ((r >> 1) & 3) : (r & 7)));
        fbh[j] = *(const bf16x8*)&lds[8192 + slot * 8];
        if (SPLIT) fbl[j] = *(const bf16x8*)&lds[12288 + slot * 8];
      }
      #pragma unroll
      for (int i = 0; i < 4; ++i) {
        int r    = wm * 64 + i * 16 + (lane & 15);
        int kb   = (lane >> 4) + kk * 4;
        int slot = r * KB8 + (kb ^ (SPLIT ? ((r >> 1) & 3) : (r & 7)));
        bf16x8 fah = *(const bf16x8*)&lds[slot * 8];
        bf16x8 fal = fah;
        if (SPLIT) fal = *(const bf16x8*)&lds[4096 + slot * 8];
        #pragma unroll
        for (int j = 0; j < 4; ++j) {
          acc[i][j] = __builtin_amdgcn_mfma_f32_16x16x32_bf16(fah, fbh[j], acc[i][j], 0, 0, 0);
          if (SPLIT) {
            acc[i][j] = __builtin_amdgcn_mfma_f32_16x16x32_bf16(fah, fbl[j], acc[i][j], 0, 0, 0);
            acc[i][j] = __builtin_amdgcn_mfma_f32_16x16x32_bf16(fal, fbh[j], acc[i][j], 0, 0, 0);
          }
        }
      }
    }
    __syncthreads();
  }

  // epilogue: C/D layout col=lane&15, row=(lane>>4)*4+reg  [m89-verified]
  #pragma unroll
  for (int i = 0; i < 4; ++i) {
    #pragma unroll
    for (int j = 0; j < 4; ++j) {
      #pragma unroll
      for (int t = 0; t < 4; ++t) {
        long rg = m0 + wm * 64 + i * 16 + (lane >> 4) * 4 + t;
        long cg = n0 + wn * 64 + j * 16 + (lane & 15);
        float v = acc[i][j][t];
        if (MODE == 0) {
          ((float*)Cp)[bz * sCb + rg * ldC + cg] = v;
        } else if (MODE == 1) {
          ((unsigned short*)Cp)[bz * sCb + rg * ldC + cg] = f2bf_rne(v);
        } else if (MODE == 2) {
          long qq = rg & 1023, bb = rg >> 10;
          ((float*)Cp)[(qq * 16 + bb) * 1024 + cg] = tanhf(v);
        } else {
          unsigned short hv = f2bf_rne(v);
          unsigned short lv = f2bf_rne(v - bf2f(hv));
          P1[rg * 1024 + cg] = hv;
          P2[rg * 1024 + cg] = lv;
          long bb = rg & 15, qq = rg >> 4;
          ((unsigned short*)Cp)[(bb * 1024 + qq) * 2048 + 1024 + cg] = hv;
        }
      }
    }
  }
}

// ============================================================================
extern "C" void kernel_launch(void* const* d_in, const int* in_sizes, int n_in,
                              void* d_out, int out_size, void* d_ws, size_t ws_size,
                              hipStream_t stream)
{
  const float* q    = (const float*)d_in[0];   // [1024,16,1024]
  const float* c    = (const float*)d_in[1];   // [2048,16,1024]
  const float* Win  = (const float*)d_in[2];   // [1024,1024]
  const float* Wout = (const float*)d_in[3];   // [1024,2048]

  char* ws = (char*)d_ws;
  const size_t MB = 1024u * 1024u;

  unsigned short* qh  = (unsigned short*)(ws);             // region A phase 1
  unsigned short* ch  = (unsigned short*)(ws);             // region A phase 2
  unsigned short* pb  = (unsigned short*)(ws);             // region A phase 3
  unsigned short* qbh = (unsigned short*)(ws + 64 * MB);   // region B phase 1
  unsigned short* qbl = (unsigned short*)(ws + 96 * MB);
  unsigned short* ct  = (unsigned short*)(ws + 64 * MB);   // region B phase 2
  unsigned short* cat = (unsigned short*)(ws + 128 * MB);  // region C
  unsigned short* Wh  = (unsigned short*)(ws + 192 * MB);
  unsigned short* Wl  = (unsigned short*)(ws + 194 * MB);
  unsigned short* Wo  = (unsigned short*)(ws + 196 * MB);

  unsigned short* ql  = (unsigned short*)d_out;            // out-region scratch
  unsigned short* cl  = (unsigned short*)d_out;            // out-region scratch
  float* out0  = (float*)d_out;                            // [1024,16,1024]
  float* score = (float*)d_out + 16777216;                 // [16,1024,2048]

  // phase 1: splits/converts needed by G1
  split_kernel<<<16384, 256, 0, stream>>>(q,    qh, ql,      4194304L);
  split_kernel<<<1024,  256, 0, stream>>>(Win,  Wh, Wl,      262144L);
  split_kernel<<<2048,  256, 0, stream>>>(Wout, Wo, nullptr, 524288L);

  // G1: qb = q @ Win^T  (split x split), M=16384 (rows q*16+b), N=1024, K=1024
  // epilogue -> qb_hi/qb_lo + cat[...,1024:2048]
  gemm_kernel<1, 3><<<dim3(128, 8, 1), 256, 0, stream>>>(
      qh, ql, 0L, 1024L, Wh, Wl, 0L, 1024L,
      (void*)cat, 0L, 0L, qbh, qbl, 1024);

  // phase 2: split c (q_hi/q_lo now dead)
  split_kernel<<<32768, 256, 0, stream>>>(c, ch, cl, 8388608L);

  // G2: logits[b][q][k] = qb[b,q,:] . c[k,b,:]  (split x split)
  gemm_kernel<1, 0><<<dim3(8, 16, 16), 256, 0, stream>>>(
      qbh, qbl, 1024L, 16384L, ch, cl, 1024L, 16384L,
      (void*)score, 2097152L, 2048L, nullptr, nullptr, 1024);

  // phase 3 (qb/c_hi/c_lo dead): transpose c, softmax in place
  transpose_kernel<<<dim3(32, 16, 16), 256, 0, stream>>>(c, ct);
  softmax_kernel<<<16384, 256, 0, stream>>>(score, pb);

  // G4: ctx[b][q][d] = P[b,q,:] . ct[b,d,:]  -> cat[...,0:1024] bf16
  gemm_kernel<0, 1><<<dim3(8, 8, 16), 256, 0, stream>>>(
      pb, nullptr, 2097152L, 2048L, ct, nullptr, 2097152L, 2048L,
      (void*)cat, 2097152L, 2048L, nullptr, nullptr, 2048);

  // G5: out[(q*16+b)*1024+d] = tanh(cat[b*1024+q,:] . Wout[d,:])
  gemm_kernel<0, 2><<<dim3(128, 8, 1), 256, 0, stream>>>(
      cat, nullptr, 0L, 2048L, Wo, nullptr, 0L, 2048L,
      (void*)out0, 0L, 0L, nullptr, nullptr, 2048);

  (void)in_sizes; (void)n_in; (void)out_size; (void)ws_size;
}

// Round 2
// 962.614 us; speedup vs baseline: 1.0876x; 1.0876x over previous
//
#include <hip/hip_runtime.h>
#include <hip/hip_bf16.h>
#include <stdint.h>

// ============================================================================
// Attn_50233937494279: qb=q@Win^T; S=softmax(qb@c^T); ctx=S@c;
//                      out=tanh([ctx|qb]@Wout^T); returns (out[q,b,d], S[b,q,k])
//
// R1 -> R2 change: XCD-aware block swizzle in gemm_kernel. R1 rocprof showed
// G2 FETCH=1.07GB (5.6x essential) because each XCD swept the full 8MB B per
// batch through its private 4MB L2 (x-major dispatch gives XCD i one m-tile x
// ALL n-tiles). Now each XCD owns a compact m x n sub-grid (working set <=
// 4MB): G2 4x4, G1/G5 32x4 (n fastest -> A tile read once), G4 4x2.
//
// Precision: GEMM1/GEMM2 (pre-softmax) 3-term split-bf16; G4/G5 plain bf16.
// Workspace layout (200 MB), region reuse across stream-ordered phases:
//   A @ 0      (64MB): q_hi -> c_hi (after G1) -> p_bf16 (after G2)
//   B @ 64MB   (64MB): qb_hi+qb_lo -> ct (c transposed, after G2)
//   C @ 128MB  (64MB): cat = [ctx | qb] bf16
//   W @ 192MB  ( 8MB): Win_hi, Win_lo, Wout_bf16
//   d_out out-region (64MB, unused until G5): q_lo -> c_lo scratch
// ============================================================================

typedef __bf16 bf16x8 __attribute__((ext_vector_type(8)));
typedef float floatx4 __attribute__((ext_vector_type(4)));

__device__ __forceinline__ unsigned short f2bf_rne(float f) {
  unsigned int u = __float_as_uint(f);
  u += 0x7FFFu + ((u >> 16) & 1u);
  return (unsigned short)(u >> 16);
}
__device__ __forceinline__ float bf2f(unsigned short h) {
  return __uint_as_float(((unsigned int)h) << 16);
}

__device__ __forceinline__ void async_load16(const void* g, void* l) {
  __builtin_amdgcn_global_load_lds(
      (const __attribute__((address_space(1))) void*)g,
      (__attribute__((address_space(3))) void*)l,
      16, 0, 0);
}

// ----------------------------------------------------------------------------
// split fp32 -> bf16 hi/lo (lo==nullptr: plain convert). One float4 per thread.
// ----------------------------------------------------------------------------
__global__ __launch_bounds__(256) void split_kernel(
    const float* __restrict__ x, unsigned short* __restrict__ hi,
    unsigned short* __restrict__ lo, long n4)
{
  long i = (long)blockIdx.x * 256 + threadIdx.x;
  if (i >= n4) return;
  float4 v = ((const float4*)x)[i];
  ushort4 h;
  h.x = f2bf_rne(v.x); h.y = f2bf_rne(v.y);
  h.z = f2bf_rne(v.z); h.w = f2bf_rne(v.w);
  ((ushort4*)hi)[i] = h;
  if (lo) {
    ushort4 l;
    l.x = f2bf_rne(v.x - bf2f(h.x));
    l.y = f2bf_rne(v.y - bf2f(h.y));
    l.z = f2bf_rne(v.z - bf2f(h.z));
    l.w = f2bf_rne(v.w - bf2f(h.w));
    ((ushort4*)lo)[i] = l;
  }
}

// ----------------------------------------------------------------------------
// ct[b][d][k] = bf16(c[k][b][d]).  64x64 tiles via LDS.
// grid: (k_tiles=32, d_tiles=16, b=16)
// ----------------------------------------------------------------------------
__global__ __launch_bounds__(256) void transpose_kernel(
    const float* __restrict__ c, unsigned short* __restrict__ ct)
{
  __shared__ unsigned short t[64 * 68];
  int k0 = blockIdx.x * 64;
  int d0 = blockIdx.y * 64;
  int b  = blockIdx.z;
  int tid = threadIdx.x;
  #pragma unroll
  for (int p4 = 0; p4 < 4; ++p4) {
    int idx = p4 * 256 + tid;
    int kr = idx >> 4;
    int dc = (idx & 15) * 4;
    float4 v = *(const float4*)&c[(long)(k0 + kr) * 16384 + (long)b * 1024 + d0 + dc];
    ushort4 h;
    h.x = f2bf_rne(v.x); h.y = f2bf_rne(v.y);
    h.z = f2bf_rne(v.z); h.w = f2bf_rne(v.w);
    *(ushort4*)&t[kr * 68 + dc] = h;
  }
  __syncthreads();
  #pragma unroll
  for (int p4 = 0; p4 < 4; ++p4) {
    int idx = p4 * 256 + tid;
    int dr = idx >> 4;
    int kc = (idx & 15) * 4;
    ushort4 o;
    o.x = t[(kc + 0) * 68 + dr];
    o.y = t[(kc + 1) * 68 + dr];
    o.z = t[(kc + 2) * 68 + dr];
    o.w = t[(kc + 3) * 68 + dr];
    *(ushort4*)&ct[(long)b * 2097152 + (long)(d0 + dr) * 2048 + k0 + kc] = o;
  }
}

// ----------------------------------------------------------------------------
// row softmax over 2048 fp32 (in place) + bf16 copy for the ctx GEMM.
// one 256-thread block per row.
// ----------------------------------------------------------------------------
__global__ __launch_bounds__(256) void softmax_kernel(
    float* __restrict__ S, unsigned short* __restrict__ P)
{
  __shared__ float sred[8];
  long row = blockIdx.x;
  float* p = S + row * 2048;
  int tid = threadIdx.x;
  int lane = tid & 63, w = tid >> 6;
  float4 v0 = ((float4*)p)[tid];
  float4 v1 = ((float4*)p)[tid + 256];
  float m = fmaxf(fmaxf(fmaxf(v0.x, v0.y), fmaxf(v0.z, v0.w)),
                  fmaxf(fmaxf(v1.x, v1.y), fmaxf(v1.z, v1.w)));
  #pragma unroll
  for (int off = 32; off; off >>= 1) m = fmaxf(m, __shfl_xor(m, off));
  if (lane == 0) sred[w] = m;
  __syncthreads();
  m = fmaxf(fmaxf(sred[0], sred[1]), fmaxf(sred[2], sred[3]));
  v0.x = __expf(v0.x - m); v0.y = __expf(v0.y - m);
  v0.z = __expf(v0.z - m); v0.w = __expf(v0.w - m);
  v1.x = __expf(v1.x - m); v1.y = __expf(v1.y - m);
  v1.z = __expf(v1.z - m); v1.w = __expf(v1.w - m);
  float s = v0.x + v0.y + v0.z + v0.w + v1.x + v1.y + v1.z + v1.w;
  #pragma unroll
  for (int off = 32; off; off >>= 1) s += __shfl_xor(s, off);
  if (lane == 0) sred[4 + w] = s;
  __syncthreads();
  s = sred[4] + sred[5] + sred[6] + sred[7];
  float inv = 1.0f / s;
  v0.x *= inv; v0.y *= inv; v0.z *= inv; v0.w *= inv;
  v1.x *= inv; v1.y *= inv; v1.z *= inv; v1.w *= inv;
  ((float4*)p)[tid] = v0;
  ((float4*)p)[tid + 256] = v1;
  unsigned short* pp = P + row * 2048;
  ushort4 b0, b1;
  b0.x = f2bf_rne(v0.x); b0.y = f2bf_rne(v0.y);
  b0.z = f2bf_rne(v0.z); b0.w = f2bf_rne(v0.w);
  b1.x = f2bf_rne(v1.x); b1.y = f2bf_rne(v1.y);
  b1.z = f2bf_rne(v1.z); b1.w = f2bf_rne(v1.w);
  ((ushort4*)pp)[tid] = b0;
  ((ushort4*)pp)[tid + 256] = b1;
}

// ----------------------------------------------------------------------------
// Generic TN GEMM: C[bz][m][n] = sum_k A[bz][m][k] * B[bz][n][k]
// SPLIT=1: 3-term bf16 emulation Ah*Bh + Ah*Bl + Al*Bh (BK=32).
// SPLIT=0: plain bf16 (BK=64).
// 128x128 block tile, 256 threads (4 waves 2x2, each 64x64 via 4x4 MFMA tiles).
// XCD swizzle: flat%8 = XCD; XCD owns an SM x SN sub-grid of 128-tiles
// (requires gridm = GM*SM, gridn = (8/GM)*SN); n varies fastest within the
// sub-grid so an A tile's consumers run back-to-back on one XCD.
// MODE 0: fp32 C            MODE 1: bf16 C
// MODE 2: fp32 tanh, row m=(b*1024+q) remapped to out[(q*16+b)*1024+n]
// MODE 3: split write: P1/P2 = hi/lo at [m*1024+n]; Cp = cat bf16 at
//         [( (m&15)*1024 + (m>>4) )*2048 + 1024 + n]   (m = q*16+b)
// ----------------------------------------------------------------------------
template<int SPLIT, int MODE>
__global__ __launch_bounds__(256, 2) void gemm_kernel(
    const unsigned short* __restrict__ Ah, const unsigned short* __restrict__ Al,
    long sAb, long ldA,
    const unsigned short* __restrict__ Bh, const unsigned short* __restrict__ Bl,
    long sBb, long ldB,
    void* __restrict__ Cp, long sCb, long ldC,
    unsigned short* __restrict__ P1, unsigned short* __restrict__ P2,
    int K, int SM, int SN, int GM)
{
  constexpr int BK  = SPLIT ? 32 : 64;
  constexpr int KB8 = BK / 8;             // 16B slots per tile row
  constexpr int ISS = (128 * KB8) / 256;  // global_load_lds issues per tile
  constexpr int NT  = SPLIT ? 4 : 2;
  __shared__ unsigned short lds[16384];   // 32 KB

  const int tid  = threadIdx.x;
  const int lane = tid & 63;
  const int w    = tid >> 6;
  const int wm   = w >> 1;
  const int wn   = w & 1;
  const int bz   = blockIdx.z;

  // XCD-aware remap (flat%8 assumed = XCD; locality-only heuristic)
  const int flat = blockIdx.x + gridDim.x * blockIdx.y;
  const int sub  = flat & 7;
  const int g    = flat >> 3;
  const long mt  = (long)(sub % GM) * SM + (g / SN);
  const long nt  = (long)(sub / GM) * SN + (g % SN);
  const long m0  = mt * 128;
  const long n0  = nt * 128;

  const unsigned short* a0 = Ah + bz * sAb + m0 * ldA;
  const unsigned short* a1 = SPLIT ? (Al + bz * sAb + m0 * ldA) : a0;
  const unsigned short* b0 = Bh + bz * sBb + n0 * ldB;
  const unsigned short* b1 = SPLIT ? (Bl + bz * sBb + n0 * ldB) : b0;

  floatx4 acc[4][4] = {};

  for (int kt = 0; kt < K; kt += BK) {
    #pragma unroll
    for (int t = 0; t < NT; ++t) {
      const unsigned short* src;
      long ld;
      int base;
      if (SPLIT) {
        src  = (t == 0) ? a0 : (t == 1) ? a1 : (t == 2) ? b0 : b1;
        ld   = (t < 2) ? ldA : ldB;
        base = t * 4096;
      } else {
        src  = (t == 0) ? a0 : b0;
        ld   = (t == 0) ? ldA : ldB;
        base = t * 8192;
      }
      #pragma unroll
      for (int it = 0; it < ISS; ++it) {
        int s   = it * 256 + tid;
        int row = s / KB8;
        int kb  = (s & (KB8 - 1)) ^ (SPLIT ? ((row >> 1) & 3) : (row & 7));
        const unsigned short* g2 = src + (long)row * ld + kt + kb * 8;
        async_load16(g2, &lds[base + (it * 256 + w * 64) * 8]);
      }
    }
    __syncthreads();

    #pragma unroll
    for (int kk = 0; kk < BK / 32; ++kk) {
      bf16x8 fbh[4], fbl[4];
      #pragma unroll
      for (int j = 0; j < 4; ++j) {
        int r    = wn * 64 + j * 16 + (lane & 15);
        int kb   = (lane >> 4) + kk * 4;
        int slot = r * KB8 + (kb ^ (SPLIT ? ((r >> 1) & 3) : (r & 7)));
        fbh[j] = *(const bf16x8*)&lds[8192 + slot * 8];
        if (SPLIT) fbl[j] = *(const bf16x8*)&lds[12288 + slot * 8];
      }
      #pragma unroll
      for (int i = 0; i < 4; ++i) {
        int r    = wm * 64 + i * 16 + (lane & 15);
        int kb   = (lane >> 4) + kk * 4;
        int slot = r * KB8 + (kb ^ (SPLIT ? ((r >> 1) & 3) : (r & 7)));
        bf16x8 fah = *(const bf16x8*)&lds[slot * 8];
        bf16x8 fal = fah;
        if (SPLIT) fal = *(const bf16x8*)&lds[4096 + slot * 8];
        #pragma unroll
        for (int j = 0; j < 4; ++j) {
          acc[i][j] = __builtin_amdgcn_mfma_f32_16x16x32_bf16(fah, fbh[j], acc[i][j], 0, 0, 0);
          if (SPLIT) {
            acc[i][j] = __builtin_amdgcn_mfma_f32_16x16x32_bf16(fah, fbl[j], acc[i][j], 0, 0, 0);
            acc[i][j] = __builtin_amdgcn_mfma_f32_16x16x32_bf16(fal, fbh[j], acc[i][j], 0, 0, 0);
          }
        }
      }
    }
    __syncthreads();
  }

  // epilogue: C/D layout col=lane&15, row=(lane>>4)*4+reg  [m89-verified]
  #pragma unroll
  for (int i = 0; i < 4; ++i) {
    #pragma unroll
    for (int j = 0; j < 4; ++j) {
      #pragma unroll
      for (int t = 0; t < 4; ++t) {
        long rg = m0 + wm * 64 + i * 16 + (lane >> 4) * 4 + t;
        long cg = n0 + wn * 64 + j * 16 + (lane & 15);
        float v = acc[i][j][t];
        if (MODE == 0) {
          ((float*)Cp)[bz * sCb + rg * ldC + cg] = v;
        } else if (MODE == 1) {
          ((unsigned short*)Cp)[bz * sCb + rg * ldC + cg] = f2bf_rne(v);
        } else if (MODE == 2) {
          long qq = rg & 1023, bb = rg >> 10;
          ((float*)Cp)[(qq * 16 + bb) * 1024 + cg] = tanhf(v);
        } else {
          unsigned short hv = f2bf_rne(v);
          unsigned short lv = f2bf_rne(v - bf2f(hv));
          P1[rg * 1024 + cg] = hv;
          P2[rg * 1024 + cg] = lv;
          long bb = rg & 15, qq = rg >> 4;
          ((unsigned short*)Cp)[(bb * 1024 + qq) * 2048 + 1024 + cg] = hv;
        }
      }
    }
  }
}

// ============================================================================
extern "C" void kernel_launch(void* const* d_in, const int* in_sizes, int n_in,
                              void* d_out, int out_size, void* d_ws, size_t ws_size,
                              hipStream_t stream)
{
  const float* q    = (const float*)d_in[0];   // [1024,16,1024]
  const float* c    = (const float*)d_in[1];   // [2048,16,1024]
  const float* Win  = (const float*)d_in[2];   // [1024,1024]
  const float* Wout = (const float*)d_in[3];   // [1024,2048]

  char* ws = (char*)d_ws;
  const size_t MB = 1024u * 1024u;

  unsigned short* qh  = (unsigned short*)(ws);             // region A phase 1
  unsigned short* ch  = (unsigned short*)(ws);             // region A phase 2
  unsigned short* pb  = (unsigned short*)(ws);             // region A phase 3
  unsigned short* qbh = (unsigned short*)(ws + 64 * MB);   // region B phase 1
  unsigned short* qbl = (unsigned short*)(ws + 96 * MB);
  unsigned short* ct  = (unsigned short*)(ws + 64 * MB);   // region B phase 2
  unsigned short* cat = (unsigned short*)(ws + 128 * MB);  // region C
  unsigned short* Wh  = (unsigned short*)(ws + 192 * MB);
  unsigned short* Wl  = (unsigned short*)(ws + 194 * MB);
  unsigned short* Wo  = (unsigned short*)(ws + 196 * MB);

  unsigned short* ql  = (unsigned short*)d_out;            // out-region scratch
  unsigned short* cl  = (unsigned short*)d_out;            // out-region scratch
  float* out0  = (float*)d_out;                            // [1024,16,1024]
  float* score = (float*)d_out + 16777216;                 // [16,1024,2048]

  // phase 1: splits/converts needed by G1
  split_kernel<<<16384, 256, 0, stream>>>(q,    qh, ql,      4194304L);
  split_kernel<<<1024,  256, 0, stream>>>(Win,  Wh, Wl,      262144L);
  split_kernel<<<2048,  256, 0, stream>>>(Wout, Wo, nullptr, 524288L);

  // G1: qb = q @ Win^T  (split x split), M=16384 (rows q*16+b), N=1024, K=1024
  // XCD sub-grid 32m x 4n
  gemm_kernel<1, 3><<<dim3(128, 8, 1), 256, 0, stream>>>(
      qh, ql, 0L, 1024L, Wh, Wl, 0L, 1024L,
      (void*)cat, 0L, 0L, qbh, qbl, 1024, 32, 4, 4);

  // phase 2: split c (q_hi/q_lo now dead)
  split_kernel<<<32768, 256, 0, stream>>>(c, ch, cl, 8388608L);

  // G2: logits[b][q][k] = qb[b,q,:] . c[k,b,:]  (split x split)
  // XCD sub-grid 4m x 4n  (working set 4MB = one XCD L2)
  gemm_kernel<1, 0><<<dim3(8, 16, 16), 256, 0, stream>>>(
      qbh, qbl, 1024L, 16384L, ch, cl, 1024L, 16384L,
      (void*)score, 2097152L, 2048L, nullptr, nullptr, 1024, 4, 4, 2);

  // phase 3 (qb/c_hi/c_lo dead): transpose c, softmax in place
  transpose_kernel<<<dim3(32, 16, 16), 256, 0, stream>>>(c, ct);
  softmax_kernel<<<16384, 256, 0, stream>>>(score, pb);

  // G4: ctx[b][q][d] = P[b,q,:] . ct[b,d,:]  -> cat[...,0:1024] bf16
  // XCD sub-grid 4m x 2n
  gemm_kernel<0, 1><<<dim3(8, 8, 16), 256, 0, stream>>>(
      pb, nullptr, 2097152L, 2048L, ct, nullptr, 2097152L, 2048L,
      (void*)cat, 2097152L, 2048L, nullptr, nullptr, 2048, 4, 2, 2);

  // G5: out[(q*16+b)*1024+d] = tanh(cat[b*1024+q,:] . Wout[d,:])
  // XCD sub-grid 32m x 4n
  gemm_kernel<0, 2><<<dim3(128, 8, 1), 256, 0, stream>>>(
      cat, nullptr, 0L, 2048L, Wo, nullptr, 0L, 2048L,
      (void*)out0, 0L, 0L, nullptr, nullptr, 2048, 32, 4, 4);

  (void)in_sizes; (void)n_in; (void)out_size; (void)ws_size;
}